// Round 3
// baseline (418.882 us; speedup 1.0000x reference)
//
#include <hip/hip_runtime.h>

#define NN 1024
#define FF 64
#define NBT 64

typedef float f32x4 __attribute__((ext_vector_type(4)));
typedef short s16x8 __attribute__((ext_vector_type(8)));

__device__ __forceinline__ short f2bf(float f) {
    unsigned u = __builtin_bit_cast(unsigned, f);
    u = (u + 0x7FFFu + ((u >> 16) & 1u)) >> 16;
    return (short)u;
}

// Kernel 1: Wh = h @ W (fp32 compute). Outputs:
//   WhT  bf16  [bt][c][j]   (transposed so k2 B-fragments are contiguous in j)
//   s1,s2 fp32 [bt][j]
__global__ __launch_bounds__(256) void k1(const float* __restrict__ h,
                                          const float* __restrict__ W,
                                          const float* __restrict__ a,
                                          short* __restrict__ WhT,
                                          float* __restrict__ s1g,
                                          float* __restrict__ s2g) {
    __shared__ float Wl[64 * 64];   // [k][c]
    __shared__ float al[128];
    __shared__ float s1sh[128], s2sh[128];
    const int blk = blockIdx.x;
    const int bt = blk >> 3;
    const int rbase = (blk & 7) * 128;
    const int t = threadIdx.x;

    for (int i = t; i < 1024; i += 256)
        ((f32x4*)Wl)[i] = ((const f32x4*)W)[i];
    if (t < 32) ((f32x4*)al)[t] = ((const f32x4*)a)[t];
    __syncthreads();

    const int row = rbase + (t & 127);
    const int half = t >> 7;           // 0: c 0..31, 1: c 32..63
    const float* hrow = h + ((size_t)bt * NN + row) * FF;
    float hv[64];
#pragma unroll
    for (int i = 0; i < 16; i++)
        ((f32x4*)hv)[i] = ((const f32x4*)hrow)[i];

    float s1 = 0.f, s2 = 0.f;
    short* wt = WhT + (size_t)bt * FF * NN + row;
#pragma unroll
    for (int cgi = 0; cgi < 8; cgi++) {
        const int cg = half * 8 + cgi;       // float4 group of columns
        f32x4 acc = {0.f, 0.f, 0.f, 0.f};
#pragma unroll
        for (int k = 0; k < 64; k++) {
            f32x4 w4 = ((const f32x4*)Wl)[k * 16 + cg];  // broadcast read
            acc += hv[k] * w4;
        }
        const int c0 = cg * 4;
        s1 += acc.x * al[c0] + acc.y * al[c0 + 1] + acc.z * al[c0 + 2] + acc.w * al[c0 + 3];
        s2 += acc.x * al[64 + c0] + acc.y * al[64 + c0 + 1] + acc.z * al[64 + c0 + 2] + acc.w * al[64 + c0 + 3];
        wt[(size_t)(c0 + 0) * NN] = f2bf(acc.x);
        wt[(size_t)(c0 + 1) * NN] = f2bf(acc.y);
        wt[(size_t)(c0 + 2) * NN] = f2bf(acc.z);
        wt[(size_t)(c0 + 3) * NN] = f2bf(acc.w);
    }
    if (half == 1) { s1sh[t & 127] = s1; s2sh[t & 127] = s2; }
    __syncthreads();
    if (half == 0) {
        s1g[bt * NN + row] = s1 + s1sh[t];
        s2g[bt * NN + row] = s2 + s2sh[t];
    }
}

// Kernel 2 (barrier-free): each wave owns 32 rows. Each lane computes its own
// MFMA A-fragment (P values for row m=lane&15 [+16], j = jt*32+q*8..+7) in
// registers from adj + s1 + s2; B-fragments load straight from WhT[c][j]
// (16B contiguous, L2-hot). No K-loop barriers -> fine-grained vmcnt, latency
// hidden across waves. grid 512 = 64 batches x 8 row-tiles(128); 4 waves.
__global__ __launch_bounds__(256) void k2(const int* __restrict__ adj,
                                          const short* __restrict__ WhT,
                                          const float* __restrict__ s1g,
                                          const float* __restrict__ s2g,
                                          float* __restrict__ out) {
    __shared__ float s2l[NN];

    const int bx = blockIdx.x;
    const int bt = bx >> 3;            // batch
    const int ib = (bx & 7) * 128;     // row-tile base
    const int t = threadIdx.x;
    const int wv = t >> 6;
    const int l = t & 63;
    const int m = l & 15;
    const int q = l >> 4;

    // stage this batch's s2 row (reused by all 32 j-tiles)
    ((f32x4*)s2l)[t] = ((const f32x4*)(s2g + bt * NN))[t];

    const int r0 = ib + wv * 32 + m;
    const int r1 = r0 + 16;
    const float s1a = s1g[bt * NN + r0];
    const float s1b = s1g[bt * NN + r1];

    const int* ap0 = adj + ((size_t)bt * NN + r0) * NN + q * 8;
    const int* ap1 = adj + ((size_t)bt * NN + r1) * NN + q * 8;
    const short* wb = WhT + (size_t)bt * FF * NN + q * 8;
    const short* bq0 = wb + (size_t)(0 * 16 + m) * NN;
    const short* bq1 = wb + (size_t)(1 * 16 + m) * NN;
    const short* bq2 = wb + (size_t)(2 * 16 + m) * NN;
    const short* bq3 = wb + (size_t)(3 * 16 + m) * NN;

    f32x4 acc[8];
#pragma unroll
    for (int i = 0; i < 8; i++) acc[i] = (f32x4){0.f, 0.f, 0.f, 0.f};
    float rs0 = 0.f, rs1 = 0.f;

    // prefetch tile 0
    int4 ca00 = *(const int4*)(ap0);
    int4 ca01 = *(const int4*)(ap0 + 4);
    int4 ca10 = *(const int4*)(ap1);
    int4 ca11 = *(const int4*)(ap1 + 4);
    s16x8 cb0 = *(const s16x8*)(bq0);
    s16x8 cb1 = *(const s16x8*)(bq1);
    s16x8 cb2 = *(const s16x8*)(bq2);
    s16x8 cb3 = *(const s16x8*)(bq3);

    __syncthreads();   // s2l ready (only barrier in the kernel)

    for (int jt = 0; jt < 32; jt++) {
        const int off = (jt < 31 ? jt + 1 : 31) * 32;
        int4 na00 = *(const int4*)(ap0 + off);
        int4 na01 = *(const int4*)(ap0 + off + 4);
        int4 na10 = *(const int4*)(ap1 + off);
        int4 na11 = *(const int4*)(ap1 + off + 4);
        s16x8 nb0 = *(const s16x8*)(bq0 + off);
        s16x8 nb1 = *(const s16x8*)(bq1 + off);
        s16x8 nb2 = *(const s16x8*)(bq2 + off);
        s16x8 nb3 = *(const s16x8*)(bq3 + off);

        f32x4 s2a = *(const f32x4*)&s2l[jt * 32 + q * 8];
        f32x4 s2b = *(const f32x4*)&s2l[jt * 32 + q * 8 + 4];
        const float sv[8] = {s2a.x, s2a.y, s2a.z, s2a.w, s2b.x, s2b.y, s2b.z, s2b.w};

        const int aj0[8] = {ca00.x, ca00.y, ca00.z, ca00.w, ca01.x, ca01.y, ca01.z, ca01.w};
        const int aj1[8] = {ca10.x, ca10.y, ca10.z, ca10.w, ca11.x, ca11.y, ca11.z, ca11.w};
        s16x8 pa0, pa1;
#pragma unroll
        for (int u = 0; u < 8; u++) {
            float e0 = s1a + sv[u];
            e0 = fmaxf(e0, 0.2f * e0);          // leaky_relu (alpha<1)
            e0 = fminf(e0, 60.f);
            float p0 = (aj0[u] > 0) ? __expf(e0) : 0.f;
            rs0 += p0;
            pa0[u] = f2bf(p0);

            float e1 = s1b + sv[u];
            e1 = fmaxf(e1, 0.2f * e1);
            e1 = fminf(e1, 60.f);
            float p1 = (aj1[u] > 0) ? __expf(e1) : 0.f;
            rs1 += p1;
            pa1[u] = f2bf(p1);
        }

        acc[0] = __builtin_amdgcn_mfma_f32_16x16x32_bf16(pa0, cb0, acc[0], 0, 0, 0);
        acc[1] = __builtin_amdgcn_mfma_f32_16x16x32_bf16(pa0, cb1, acc[1], 0, 0, 0);
        acc[2] = __builtin_amdgcn_mfma_f32_16x16x32_bf16(pa0, cb2, acc[2], 0, 0, 0);
        acc[3] = __builtin_amdgcn_mfma_f32_16x16x32_bf16(pa0, cb3, acc[3], 0, 0, 0);
        acc[4] = __builtin_amdgcn_mfma_f32_16x16x32_bf16(pa1, cb0, acc[4], 0, 0, 0);
        acc[5] = __builtin_amdgcn_mfma_f32_16x16x32_bf16(pa1, cb1, acc[5], 0, 0, 0);
        acc[6] = __builtin_amdgcn_mfma_f32_16x16x32_bf16(pa1, cb2, acc[6], 0, 0, 0);
        acc[7] = __builtin_amdgcn_mfma_f32_16x16x32_bf16(pa1, cb3, acc[7], 0, 0, 0);

        ca00 = na00; ca01 = na01; ca10 = na10; ca11 = na11;
        cb0 = nb0; cb1 = nb1; cb2 = nb2; cb3 = nb3;
    }

    // row-sum reduce across the 4 q-lanes holding the same row
    rs0 += __shfl_xor(rs0, 16);
    rs0 += __shfl_xor(rs0, 32);
    rs1 += __shfl_xor(rs1, 16);
    rs1 += __shfl_xor(rs1, 32);

    // C layout: D[row=q*4+e][col=m] per 16-col group. rs for tile-row ro lives in lane ro.
    float* ob = out + ((size_t)bt * NN + ib + wv * 32) * FF + m;
#pragma unroll
    for (int e = 0; e < 4; e++) {
        const int ro = q * 4 + e;
        float rA = __shfl(rs0, ro);
        float rB = __shfl(rs1, ro);
        float iA = rA > 0.f ? 1.f / rA : 0.f;
        float iB = rB > 0.f ? 1.f / rB : 0.f;
#pragma unroll
        for (int cg = 0; cg < 4; cg++) {
            float v = acc[cg][e] * iA;
            v = v > 0.f ? v : (__expf(v) - 1.f);   // elu
            ob[(size_t)ro * FF + cg * 16] = v;
            float w = acc[4 + cg][e] * iB;
            w = w > 0.f ? w : (__expf(w) - 1.f);
            ob[(size_t)(16 + ro) * FF + cg * 16] = w;
        }
    }
}

extern "C" void kernel_launch(void* const* d_in, const int* in_sizes, int n_in,
                              void* d_out, int out_size, void* d_ws, size_t ws_size,
                              hipStream_t stream) {
    const float* h  = (const float*)d_in[0];
    const int*  adj = (const int*)d_in[1];
    const float* W  = (const float*)d_in[2];
    const float* a  = (const float*)d_in[3];
    float* out = (float*)d_out;

    short* WhT = (short*)d_ws;                                      // 8 MB
    float* s1  = (float*)((char*)d_ws + (size_t)NBT * FF * NN * 2);
    float* s2  = s1 + NBT * NN;

    k1<<<512, 256, 0, stream>>>(h, W, a, WhT, s1, s2);
    k2<<<512, 256, 0, stream>>>(adj, WhT, s1, s2, out);
}